// Round 18
// baseline (143.471 us; speedup 1.0000x reference)
//
#include <hip/hip_runtime.h>
#include <hip/hip_bf16.h>
#include <cstdint>
#include <cstddef>

#define T_DIM 8
#define N_NODES 50000
#define F_DIM 64
#define H_DIM 32
#define L_DIM 64
#define E_EDGES 800000

#define NB 128            // dst bins per t
#define NPB 391           // nodes per bin (128*391 = 50048 >= 50000)
#define BIN_CAP 8192      // global slots per (t,bin)
#define CHUNK_A 2000      // edges per k_part block (400 blocks per t; 18KB LDS -> 8 blk/CU)
#define DF_CAP 7400       // k_degfill cap (mean 6250 + 14 sigma)
#define NPB3 256          // nodes per k_gather4 block (work-stealing pool)
#define NBLK_G3 196       // ceil(N_NODES/256)
#define CSTAGE (2 * DF_CAP)  // 14800: len0+len1 <= 2*DF_CAP ALWAYS (degfill clamp)

typedef __attribute__((ext_vector_type(8))) short short8;
typedef __attribute__((ext_vector_type(4))) float f32x4;

__device__ __forceinline__ unsigned short f2bf(float f) {
  unsigned u = __float_as_uint(f);
  u = u + 0x7FFFu + ((u >> 16) & 1u);   // round-to-nearest-even
  return (unsigned short)(u >> 16);
}
__device__ __forceinline__ float bf2f(unsigned short b) {
  return __uint_as_float(((unsigned)b) << 16);
}
// add 8 bf16 (packed in uint4) into f32 acc[8] via bit-ops
__device__ __forceinline__ void addbf8(float* a, uint4 u) {
  a[0] += __uint_as_float(u.x << 16);
  a[1] += __uint_as_float(u.x & 0xFFFF0000u);
  a[2] += __uint_as_float(u.y << 16);
  a[3] += __uint_as_float(u.y & 0xFFFF0000u);
  a[4] += __uint_as_float(u.z << 16);
  a[5] += __uint_as_float(u.z & 0xFFFF0000u);
  a[6] += __uint_as_float(u.w << 16);
  a[7] += __uint_as_float(u.w & 0xFFFF0000u);
}
__device__ __forceinline__ short8 pack8(float4 lo, float4 hi) {
  short8 r;
  r[0] = (short)f2bf(lo.x); r[1] = (short)f2bf(lo.y);
  r[2] = (short)f2bf(lo.z); r[3] = (short)f2bf(lo.w);
  r[4] = (short)f2bf(hi.x); r[5] = (short)f2bf(hi.y);
  r[6] = (short)f2bf(hi.z); r[7] = (short)f2bf(hi.w);
  return r;
}

// K1: radix-partition edges into 128 dst-bins per t. LDS counting-sort of the
// 2000-edge chunk + coalesced stream-out. src AND dst staged to LDS in pass 1
// so pass 2 is LDS-only. 18KB LDS -> 8 blocks/CU (R17: k_part is LDS-atomic
// latency-bound now that the global scatter is gone; occupancy pays).
// t = bid&7 pins each t's pipeline to one XCD.
__global__ void k_part(const int* __restrict__ ei, int* __restrict__ bincur,
                       int* __restrict__ binbuf) {
  int t = blockIdx.x & 7;
  int e0 = (blockIdx.x >> 3) * CHUNK_A;
  const int4* d4 = reinterpret_cast<const int4*>(ei + (size_t)(t * 2 + 1) * E_EDGES + e0);
  const int4* s4 = reinterpret_cast<const int4*>(ei + (size_t)(t * 2 + 0) * E_EDGES + e0);
  __shared__ int hist[NB], bbase[NB], loff[NB], cur[NB];
  __shared__ unsigned sorted[CHUNK_A];        // 8KB
  __shared__ unsigned short dstb[CHUNK_A];    // 4KB dst stage
  __shared__ unsigned short srcb[CHUNK_A];    // 4KB src stage
  __shared__ int wtot_sh;
  int tid = threadIdx.x;
  if (tid < NB) hist[tid] = 0;
  __syncthreads();
  // pass 1: bin histogram + src/dst stage
  for (int q = tid; q < CHUNK_A / 4; q += 256) {
    int4 d = d4[q];
    int4 s = s4[q];
    ushort4 pk, ps;
    pk.x = (unsigned short)d.x; pk.y = (unsigned short)d.y;
    pk.z = (unsigned short)d.z; pk.w = (unsigned short)d.w;
    ps.x = (unsigned short)s.x; ps.y = (unsigned short)s.y;
    ps.z = (unsigned short)s.z; ps.w = (unsigned short)s.w;
    *reinterpret_cast<ushort4*>(&dstb[4 * q]) = pk;
    *reinterpret_cast<ushort4*>(&srcb[4 * q]) = ps;
    #pragma unroll
    for (int k = 0; k < 4; ++k) {
      int dst = (k == 0) ? d.x : (k == 1) ? d.y : (k == 2) ? d.z : d.w;
      atomicAdd(&hist[dst / NPB], 1);
    }
  }
  __syncthreads();
  // 128-wide exclusive scan (2 waves) + global base reservation
  int lane = tid & 63;
  int v = (tid < NB) ? hist[tid] : 0;
  int sc = v;
  #pragma unroll
  for (int o = 1; o < 64; o <<= 1) {
    int xx = __shfl_up(sc, o, 64);
    if (lane >= o) sc += xx;
  }
  if (tid == 63) wtot_sh = sc;
  __syncthreads();
  if (tid < NB) {
    int excl = sc - v + ((tid >= 64) ? wtot_sh : 0);
    loff[tid] = excl;
    cur[tid] = excl;
    bbase[tid] = atomicAdd(&bincur[t * NB + tid], v);
  }
  __syncthreads();
  // pass 2: LDS-only scatter into sorted order
  for (int i = tid; i < CHUNK_A; i += 256) {
    int dst = dstb[i];
    int src = srcb[i];
    int b = dst / NPB;
    int dl = dst - b * NPB;
    int pos = atomicAdd(&cur[b], 1);
    sorted[pos] = ((unsigned)b << 25) | ((unsigned)dl << 16) | (unsigned)src;
  }
  __syncthreads();
  // pass 3: coalesced stream-out (consecutive i -> consecutive global pos)
  for (int i = tid; i < CHUNK_A; i += 256) {
    unsigned e = sorted[i];
    int b = e >> 25;
    int gpos = bbase[b] + (i - loff[b]);
    if (gpos < BIN_CAP)
      binbuf[(size_t)(t * NB + b) * BIN_CAP + gpos] = (int)(e & 0x01FFFFFFu);
  }
}

// K2: per-(t,bin) finalize. binbuf read twice from XCD-L2 (no LDS staging);
// LDS ~18KB -> 8 blocks/CU.
__global__ void k_degfill(const int* __restrict__ bincur, const int* __restrict__ binbuf,
                          int* __restrict__ deg, int* __restrict__ rowg,
                          unsigned short* __restrict__ colbuf) {
  int t = blockIdx.x & 7;
  int b = blockIdx.x >> 3;
  __shared__ unsigned short sbuf[DF_CAP]; // 14.8KB
  __shared__ int hist[NPB], rowoff[NPB + 1];
  __shared__ int wsum[4];
  int tid = threadIdx.x;
  int cnt = bincur[t * NB + b];
  if (cnt > DF_CAP) cnt = DF_CAP;
  const int* gbuf = binbuf + (size_t)(t * NB + b) * BIN_CAP;
  for (int i = tid; i < NPB; i += 256) hist[i] = 0;
  __syncthreads();
  for (int i = tid; i < cnt; i += 256) atomicAdd(&hist[gbuf[i] >> 16], 1);
  __syncthreads();
  int nb0 = b * NPB;
  for (int dl = tid; dl < NPB; dl += 256) {
    int n = nb0 + dl;
    if (n < N_NODES) deg[t * N_NODES + n] = hist[dl];
  }
  // block exclusive scan of hist[0..NPB)
  int i0 = 2 * tid, i1 = 2 * tid + 1;
  int a0 = (i0 < NPB) ? hist[i0] : 0;
  int a1 = (i1 < NPB) ? hist[i1] : 0;
  int tsum = a0 + a1;
  int lane = tid & 63, wid = tid >> 6;
  int sc = tsum;
  #pragma unroll
  for (int off = 1; off < 64; off <<= 1) {
    int o = __shfl_up(sc, off, 64);
    if (lane >= off) sc += o;
  }
  if (lane == 63) wsum[wid] = sc;
  __syncthreads();
  if (tid == 0) {
    int c = 0;
    for (int k = 0; k < 4; ++k) { int v = wsum[k]; wsum[k] = c; c += v; }
  }
  __syncthreads();
  int excl = wsum[wid] + (sc - tsum);
  if (i0 < NPB) rowoff[i0] = excl;
  if (i1 < NPB) rowoff[i1] = excl + a0;
  if (tid == 0) rowoff[NPB] = cnt;
  __syncthreads();
  int* rg = rowg + (size_t)(t * NB + b) * (NPB + 1);
  for (int i = tid; i <= NPB; i += 256) rg[i] = rowoff[i];
  for (int i = tid; i < NPB; i += 256) hist[i] = 0;   // reuse as cursor
  __syncthreads();
  for (int i = tid; i < cnt; i += 256) {
    int w = gbuf[i];                    // L2-hot re-read
    int dl = w >> 16;
    int pos = rowoff[dl] + atomicAdd(&hist[dl], 1);
    sbuf[pos] = (unsigned short)(w & 0xFFFF);   // LDS scatter (banked, cheap)
  }
  __syncthreads();
  unsigned short* cb = colbuf + (size_t)(t * NB + b) * BIN_CAP;
  for (int i = tid; i < cnt; i += 256) cb[i] = sbuf[i];  // coalesced ushort
}

// K3: s = rsqrt(deg+1) * (x @ conv_w) via bf16 MFMA (16x16x32), bf16 out.
// nb==0 blocks also zero seq_raw (kills the second memset dispatch; strictly
// before k_gather4's atomics).
__global__ __launch_bounds__(256) void k_xw(const float* __restrict__ x,
                                            const float* __restrict__ w,
                                            const int* __restrict__ deg,
                                            unsigned short* __restrict__ s,
                                            float* __restrict__ seq_raw) {
  int t = blockIdx.x & 7;
  int nb = blockIdx.x >> 3;
  if (nb == 0 && threadIdx.x < H_DIM) seq_raw[t * H_DIM + threadIdx.x] = 0.f;
  int wave = threadIdx.x >> 6, lane = threadIdx.x & 63;
  int node0 = nb * 64 + wave * 16;
  if (node0 >= N_NODES) return;         // 50000 = 781*64 + 16: clean tail
  int m = lane & 15, kg = lane >> 4;
  const float4* xr = reinterpret_cast<const float4*>(
      x + ((size_t)t * N_NODES + node0 + m) * F_DIM + kg * 8);
  short8 a0 = pack8(xr[0], xr[1]);      // k = kg*8 + 0..7
  short8 a1 = pack8(xr[8], xr[9]);      // k = 32 + kg*8 + 0..7
  const float* wb0 = w + (kg * 8) * H_DIM + m;
  const float* wb1 = wb0 + 32 * H_DIM;
  short8 b00, b01, b10, b11;            // b{khalf}{hhalf}
  #pragma unroll
  for (int j = 0; j < 8; ++j) {
    b00[j] = (short)f2bf(wb0[j * H_DIM]);
    b01[j] = (short)f2bf(wb0[j * H_DIM + 16]);
    b10[j] = (short)f2bf(wb1[j * H_DIM]);
    b11[j] = (short)f2bf(wb1[j * H_DIM + 16]);
  }
  f32x4 acc0 = {0.f, 0.f, 0.f, 0.f}, acc1 = {0.f, 0.f, 0.f, 0.f};
  acc0 = __builtin_amdgcn_mfma_f32_16x16x32_bf16(a0, b00, acc0, 0, 0, 0);
  acc0 = __builtin_amdgcn_mfma_f32_16x16x32_bf16(a1, b10, acc0, 0, 0, 0);
  acc1 = __builtin_amdgcn_mfma_f32_16x16x32_bf16(a0, b01, acc1, 0, 0, 0);
  acc1 = __builtin_amdgcn_mfma_f32_16x16x32_bf16(a1, b11, acc1, 0, 0, 0);
  unsigned short* sbase = s + ((size_t)t * N_NODES + node0) * H_DIM;
  #pragma unroll
  for (int r = 0; r < 4; ++r) {
    int row = kg * 4 + r;
    float dinv = rsqrtf((float)(deg[t * N_NODES + node0 + row] + 1));
    sbase[(size_t)row * H_DIM + m]      = f2bf(acc0[r] * dinv);
    sbase[(size_t)row * H_DIM + 16 + m] = f2bf(acc1[r] * dinv);
  }
}

// K4: work-stealing gather with guaranteed LDS col staging + fused pooled
// reduction (atomicAdd into seq_raw). ro_l stored as ushort (values <=
// DF_CAP < 65536): LDS 31.2KB < 32KB -> 5 blocks/CU (was 4). t = bid&7.
__global__ void k_gather4(const unsigned short* __restrict__ s,
                          const unsigned short* __restrict__ colbuf,
                          const int* __restrict__ rowg, const float* __restrict__ conv_b,
                          float* __restrict__ seq_raw) {
  int bid = blockIdx.x;
  int t = bid & 7;
  int gblk = bid >> 3;                  // 0..NBLK_G3-1
  int base = gblk * NPB3;
  int tid = threadIdx.x;
  int g = tid >> 2, j = tid & 3;        // 64 groups x 4 feature-lanes
  int lane = tid & 63;
  __shared__ unsigned short colstage[CSTAGE];     // 29.6KB
  __shared__ unsigned short ro_l[2][NPB + 1];     // 1.57KB (ushort: <= DF_CAP)
  __shared__ int nextn;
  __shared__ float red[4][32];
  if (tid == 0) nextn = 64;

  int nend = min(base + NPB3, N_NODES);
  int bin0 = base / NPB;
  int bin1 = (nend - 1) / NPB;          // bin0 or bin0+1
  const int* rg0 = rowg + (size_t)(t * NB + bin0) * (NPB + 1);
  for (int i = tid; i <= NPB; i += 256) ro_l[0][i] = (unsigned short)rg0[i];
  if (bin1 > bin0) {
    const int* rg1 = rowg + (size_t)(t * NB + bin1) * (NPB + 1);
    for (int i = tid; i <= NPB; i += 256) ro_l[1][i] = (unsigned short)rg1[i];
  }
  __syncthreads();
  int dlA0 = base - bin0 * NPB;
  int dlE0 = (bin1 > bin0) ? (NPB - 1) : (nend - 1 - bin0 * NPB);
  int s0 = ro_l[0][dlA0];
  int len0 = (int)ro_l[0][dlE0 + 1] - s0;  // <= DF_CAP
  int len1 = 0;
  if (bin1 > bin0) {
    int dlE1 = nend - 1 - bin1 * NPB;
    len1 = ro_l[1][dlE1 + 1];           // seg1 starts at within-bin offset 0
  }
  {
    const unsigned short* cb0 = colbuf + (size_t)(t * NB + bin0) * BIN_CAP + s0;
    for (int i = tid; i < len0; i += 256) colstage[i] = cb0[i];
    if (len1 > 0) {
      const unsigned short* cb1 = colbuf + (size_t)(t * NB + bin1) * BIN_CAP;
      for (int i = tid; i < len1; i += 256) colstage[len0 + i] = cb1[i];
    }
  }
  __syncthreads();

  const unsigned short* sbase = s + (size_t)t * N_NODES * H_DIM;
  const float4* cb4 = reinterpret_cast<const float4*>(conv_b);
  float4 bb0 = cb4[j * 2], bb1 = cb4[j * 2 + 1];
  float pool[8];
  #pragma unroll
  for (int e = 0; e < 8; ++e) pool[e] = 0.f;
  int idx = g;                          // initial assignment, then steal
  while (idx < NPB3) {
    int n = base + idx;
    if (n < N_NODES) {
      int b = n / NPB;
      int dl = n - b * NPB;
      int bi = b - bin0;                // 0 or 1
      int start = ro_l[bi][dl], end = ro_l[bi][dl + 1];
      int cofs = bi ? len0 : (-s0);     // int offset; p + cofs >= 0 always
      float dinv = rsqrtf((float)(end - start + 1));
      float acc[8];
      #pragma unroll
      for (int e = 0; e < 8; ++e) acc[e] = 0.f;
      uint4 su = *reinterpret_cast<const uint4*>(sbase + (size_t)n * H_DIM + j * 8);
      addbf8(acc, su);                  // self-loop row
      int p = start;
      for (; p + 8 <= end; p += 8) {    // eight independent chains
        int c0 = colstage[p + cofs],     c1 = colstage[p + 1 + cofs];
        int c2 = colstage[p + 2 + cofs], c3 = colstage[p + 3 + cofs];
        int c4 = colstage[p + 4 + cofs], c5 = colstage[p + 5 + cofs];
        int c6 = colstage[p + 6 + cofs], c7 = colstage[p + 7 + cofs];
        uint4 v0 = *reinterpret_cast<const uint4*>(sbase + (size_t)c0 * H_DIM + j * 8);
        uint4 v1 = *reinterpret_cast<const uint4*>(sbase + (size_t)c1 * H_DIM + j * 8);
        uint4 v2 = *reinterpret_cast<const uint4*>(sbase + (size_t)c2 * H_DIM + j * 8);
        uint4 v3 = *reinterpret_cast<const uint4*>(sbase + (size_t)c3 * H_DIM + j * 8);
        uint4 v4 = *reinterpret_cast<const uint4*>(sbase + (size_t)c4 * H_DIM + j * 8);
        uint4 v5 = *reinterpret_cast<const uint4*>(sbase + (size_t)c5 * H_DIM + j * 8);
        uint4 v6 = *reinterpret_cast<const uint4*>(sbase + (size_t)c6 * H_DIM + j * 8);
        uint4 v7 = *reinterpret_cast<const uint4*>(sbase + (size_t)c7 * H_DIM + j * 8);
        addbf8(acc, v0); addbf8(acc, v1); addbf8(acc, v2); addbf8(acc, v3);
        addbf8(acc, v4); addbf8(acc, v5); addbf8(acc, v6); addbf8(acc, v7);
      }
      for (; p + 4 <= end; p += 4) {
        int c0 = colstage[p + cofs],     c1 = colstage[p + 1 + cofs];
        int c2 = colstage[p + 2 + cofs], c3 = colstage[p + 3 + cofs];
        uint4 v0 = *reinterpret_cast<const uint4*>(sbase + (size_t)c0 * H_DIM + j * 8);
        uint4 v1 = *reinterpret_cast<const uint4*>(sbase + (size_t)c1 * H_DIM + j * 8);
        uint4 v2 = *reinterpret_cast<const uint4*>(sbase + (size_t)c2 * H_DIM + j * 8);
        uint4 v3 = *reinterpret_cast<const uint4*>(sbase + (size_t)c3 * H_DIM + j * 8);
        addbf8(acc, v0); addbf8(acc, v1); addbf8(acc, v2); addbf8(acc, v3);
      }
      for (; p < end; ++p) {
        int c0 = colstage[p + cofs];
        uint4 v0 = *reinterpret_cast<const uint4*>(sbase + (size_t)c0 * H_DIM + j * 8);
        addbf8(acc, v0);
      }
      pool[0] += fmaxf(acc[0] * dinv + bb0.x, 0.f);
      pool[1] += fmaxf(acc[1] * dinv + bb0.y, 0.f);
      pool[2] += fmaxf(acc[2] * dinv + bb0.z, 0.f);
      pool[3] += fmaxf(acc[3] * dinv + bb0.w, 0.f);
      pool[4] += fmaxf(acc[4] * dinv + bb1.x, 0.f);
      pool[5] += fmaxf(acc[5] * dinv + bb1.y, 0.f);
      pool[6] += fmaxf(acc[6] * dinv + bb1.z, 0.f);
      pool[7] += fmaxf(acc[7] * dinv + bb1.w, 0.f);
    }
    // steal next node (group-uniform: leader atomicAdd, broadcast in-group)
    int nn = 0;
    if ((lane & 3) == 0) nn = atomicAdd(&nextn, 1);
    nn = __shfl(nn, lane & 60, 64);
    idx = nn;
  }
  // reduce across the 16 groups of each wave (classes = lane&3)
  #pragma unroll
  for (int off = 4; off < 64; off <<= 1) {
    #pragma unroll
    for (int e = 0; e < 8; ++e) pool[e] += __shfl_xor(pool[e], off, 64);
  }
  int wid = tid >> 6;
  if (lane < 4) {
    #pragma unroll
    for (int e = 0; e < 8; ++e) red[wid][lane * 8 + e] = pool[e];
  }
  __syncthreads();
  if (tid < 32) {
    float sum = red[0][tid] + red[1][tid] + red[2][tid] + red[3][tid];
    atomicAdd(&seq_raw[t * H_DIM + tid], sum);
  }
}

// K6: gate-x precompute (all t) + sequential LSTM + fc head, one block.
__global__ void k_lstm(const float* __restrict__ seq_raw, const float* __restrict__ w_ih,
                       const float* __restrict__ b_ih, const float* __restrict__ b_hh,
                       const float* __restrict__ w_hh, const float* __restrict__ fc_w,
                       const float* __restrict__ fc_b, float* __restrict__ out) {
  __shared__ float xb[T_DIM][32];
  __shared__ float gxs[T_DIM][256];
  __shared__ float hbuf[64], cbuf[64], gates[256];
  int j = threadIdx.x;                  // 256
  if (j < T_DIM * 32) xb[j >> 5][j & 31] = seq_raw[j] * (1.0f / (float)N_NODES);
  if (j < 64) { hbuf[j] = 0.f; cbuf[j] = 0.f; }
  __syncthreads();
  float bsum = b_ih[j] + b_hh[j];
  for (int t = 0; t < T_DIM; ++t) {
    float gacc = bsum;
    #pragma unroll
    for (int k = 0; k < 32; ++k) gacc += w_ih[j * 32 + k] * xb[t][k];
    gxs[t][j] = gacc;
  }
  __syncthreads();
  for (int t = 0; t < T_DIM; ++t) {
    float g = gxs[t][j];
    #pragma unroll 8
    for (int k = 0; k < 64; ++k) g += w_hh[j * 64 + k] * hbuf[k];
    gates[j] = g;
    __syncthreads();
    if (j < 64) {
      float ii = 1.f / (1.f + expf(-gates[j]));
      float ff = 1.f / (1.f + expf(-gates[64 + j]));
      float gg = tanhf(gates[128 + j]);
      float oo = 1.f / (1.f + expf(-gates[192 + j]));
      float c = ff * cbuf[j] + ii * gg;
      cbuf[j] = c;
      hbuf[j] = oo * tanhf(c);
    }
    __syncthreads();
  }
  if (j == 0) {
    float acc = 0.f;
    for (int k = 0; k < 64; ++k) acc += hbuf[k] * fc_w[k];
    out[0] = acc + fc_b[0];
  }
}

extern "C" void kernel_launch(void* const* d_in, const int* in_sizes, int n_in,
                              void* d_out, int out_size, void* d_ws, size_t ws_size,
                              hipStream_t stream) {
  const float* x      = (const float*)d_in[0];
  const int*   ei     = (const int*)  d_in[1];
  const float* conv_w = (const float*)d_in[2];
  const float* conv_b = (const float*)d_in[3];
  const float* w_ih   = (const float*)d_in[4];
  const float* w_hh   = (const float*)d_in[5];
  const float* b_ih   = (const float*)d_in[6];
  const float* b_hh   = (const float*)d_in[7];
  const float* fc_w   = (const float*)d_in[8];
  const float* fc_b   = (const float*)d_in[9];
  float* out = (float*)d_out;

  char* wsb = (char*)d_ws;
  size_t off = 0;
  auto alloc = [&](size_t bytes) {
    void* p = wsb + off;
    off = (off + bytes + 255) & ~(size_t)255;
    return p;
  };
  int* bincur   = (int*)alloc(sizeof(int) * T_DIM * NB);                    // 4 KB
  int* binbuf   = (int*)alloc(sizeof(int) * (size_t)T_DIM * NB * BIN_CAP);  // 32 MB
  unsigned short* colbuf = (unsigned short*)alloc(sizeof(unsigned short) * (size_t)T_DIM * NB * BIN_CAP); // 16 MB
  int* deg      = (int*)alloc(sizeof(int) * T_DIM * N_NODES);               // 1.6 MB
  int* rowg     = (int*)alloc(sizeof(int) * (size_t)T_DIM * NB * (NPB + 1)); // 1.6 MB
  unsigned short* s = (unsigned short*)alloc(sizeof(unsigned short) * (size_t)T_DIM * N_NODES * H_DIM); // 25.6 MB
  float* seq_raw  = (float*)alloc(sizeof(float) * T_DIM * H_DIM);

  (void)hipMemsetAsync(bincur, 0, sizeof(int) * T_DIM * NB, stream);

  k_part<<<(E_EDGES / CHUNK_A) * T_DIM, 256, 0, stream>>>(ei, bincur, binbuf);
  k_degfill<<<NB * T_DIM, 256, 0, stream>>>(bincur, binbuf, deg, rowg, colbuf);
  k_xw<<<782 * T_DIM, 256, 0, stream>>>(x, conv_w, deg, s, seq_raw);
  k_gather4<<<NBLK_G3 * T_DIM, 256, 0, stream>>>(s, colbuf, rowg, conv_b, seq_raw);
  k_lstm<<<1, 256, 0, stream>>>(seq_raw, w_ih, b_ih, b_hh, w_hh, fc_w, fc_b, out);
}

// Round 19
// 141.933 us; speedup vs baseline: 1.0108x; 1.0108x over previous
//
#include <hip/hip_runtime.h>
#include <hip/hip_bf16.h>
#include <cstdint>
#include <cstddef>

#define T_DIM 8
#define N_NODES 50000
#define F_DIM 64
#define H_DIM 32
#define L_DIM 64
#define E_EDGES 800000

#define NB 128            // dst bins per t
#define NPB 391           // nodes per bin (128*391 = 50048 >= 50000)
#define BIN_CAP 8192      // global slots per (t,bin)
#define CHUNK_A 4000      // edges per k_part block (200 blocks per t) — R17-best
#define DF_CAP 7400       // k_degfill cap (mean 6250 + 14 sigma)
#define NPB3 256          // nodes per k_gather4 block (work-stealing pool)
#define NBLK_G3 196       // ceil(N_NODES/256)
#define CSTAGE (2 * DF_CAP)  // 14800: len0+len1 <= 2*DF_CAP ALWAYS (degfill clamp)

typedef __attribute__((ext_vector_type(8))) short short8;
typedef __attribute__((ext_vector_type(4))) float f32x4;

__device__ __forceinline__ unsigned short f2bf(float f) {
  unsigned u = __float_as_uint(f);
  u = u + 0x7FFFu + ((u >> 16) & 1u);   // round-to-nearest-even
  return (unsigned short)(u >> 16);
}
__device__ __forceinline__ float bf2f(unsigned short b) {
  return __uint_as_float(((unsigned)b) << 16);
}
// add 8 bf16 (packed in uint4) into f32 acc[8] via bit-ops
__device__ __forceinline__ void addbf8(float* a, uint4 u) {
  a[0] += __uint_as_float(u.x << 16);
  a[1] += __uint_as_float(u.x & 0xFFFF0000u);
  a[2] += __uint_as_float(u.y << 16);
  a[3] += __uint_as_float(u.y & 0xFFFF0000u);
  a[4] += __uint_as_float(u.z << 16);
  a[5] += __uint_as_float(u.z & 0xFFFF0000u);
  a[6] += __uint_as_float(u.w << 16);
  a[7] += __uint_as_float(u.w & 0xFFFF0000u);
}
__device__ __forceinline__ short8 pack8(float4 lo, float4 hi) {
  short8 r;
  r[0] = (short)f2bf(lo.x); r[1] = (short)f2bf(lo.y);
  r[2] = (short)f2bf(lo.z); r[3] = (short)f2bf(lo.w);
  r[4] = (short)f2bf(hi.x); r[5] = (short)f2bf(hi.y);
  r[6] = (short)f2bf(hi.z); r[7] = (short)f2bf(hi.w);
  return r;
}

// K1: radix-partition edges into 128 dst-bins per t. LDS counting-sort of the
// 4000-edge chunk + coalesced stream-out. src AND dst staged to LDS in pass 1
// so pass 2 is LDS-only. t = bid&7 pins each t's pipeline to one XCD.
__global__ void k_part(const int* __restrict__ ei, int* __restrict__ bincur,
                       int* __restrict__ binbuf) {
  int t = blockIdx.x & 7;
  int e0 = (blockIdx.x >> 3) * CHUNK_A;
  const int4* d4 = reinterpret_cast<const int4*>(ei + (size_t)(t * 2 + 1) * E_EDGES + e0);
  const int4* s4 = reinterpret_cast<const int4*>(ei + (size_t)(t * 2 + 0) * E_EDGES + e0);
  __shared__ int hist[NB], bbase[NB], loff[NB], cur[NB];
  __shared__ unsigned sorted[CHUNK_A];        // 16KB
  __shared__ unsigned short dstb[CHUNK_A];    // 8KB dst stage
  __shared__ unsigned short srcb[CHUNK_A];    // 8KB src stage
  __shared__ int wtot_sh;
  int tid = threadIdx.x;
  if (tid < NB) hist[tid] = 0;
  __syncthreads();
  // pass 1: bin histogram + src/dst stage
  for (int q = tid; q < CHUNK_A / 4; q += 256) {
    int4 d = d4[q];
    int4 s = s4[q];
    ushort4 pk, ps;
    pk.x = (unsigned short)d.x; pk.y = (unsigned short)d.y;
    pk.z = (unsigned short)d.z; pk.w = (unsigned short)d.w;
    ps.x = (unsigned short)s.x; ps.y = (unsigned short)s.y;
    ps.z = (unsigned short)s.z; ps.w = (unsigned short)s.w;
    *reinterpret_cast<ushort4*>(&dstb[4 * q]) = pk;
    *reinterpret_cast<ushort4*>(&srcb[4 * q]) = ps;
    #pragma unroll
    for (int k = 0; k < 4; ++k) {
      int dst = (k == 0) ? d.x : (k == 1) ? d.y : (k == 2) ? d.z : d.w;
      atomicAdd(&hist[dst / NPB], 1);
    }
  }
  __syncthreads();
  // 128-wide exclusive scan (2 waves) + global base reservation
  int lane = tid & 63;
  int v = (tid < NB) ? hist[tid] : 0;
  int sc = v;
  #pragma unroll
  for (int o = 1; o < 64; o <<= 1) {
    int xx = __shfl_up(sc, o, 64);
    if (lane >= o) sc += xx;
  }
  if (tid == 63) wtot_sh = sc;
  __syncthreads();
  if (tid < NB) {
    int excl = sc - v + ((tid >= 64) ? wtot_sh : 0);
    loff[tid] = excl;
    cur[tid] = excl;
    bbase[tid] = atomicAdd(&bincur[t * NB + tid], v);
  }
  __syncthreads();
  // pass 2: LDS-only scatter into sorted order
  for (int i = tid; i < CHUNK_A; i += 256) {
    int dst = dstb[i];
    int src = srcb[i];
    int b = dst / NPB;
    int dl = dst - b * NPB;
    int pos = atomicAdd(&cur[b], 1);
    sorted[pos] = ((unsigned)b << 25) | ((unsigned)dl << 16) | (unsigned)src;
  }
  __syncthreads();
  // pass 3: coalesced stream-out (consecutive i -> consecutive global pos)
  for (int i = tid; i < CHUNK_A; i += 256) {
    unsigned e = sorted[i];
    int b = e >> 25;
    int gpos = bbase[b] + (i - loff[b]);
    if (gpos < BIN_CAP)
      binbuf[(size_t)(t * NB + b) * BIN_CAP + gpos] = (int)(e & 0x01FFFFFFu);
  }
}

// K2: per-(t,bin) finalize. No LDS staging of binbuf (XCD-L2-resident from
// k_part's pinned writes); read it from global twice. LDS ~18KB -> 8 blk/CU.
__global__ void k_degfill(const int* __restrict__ bincur, const int* __restrict__ binbuf,
                          int* __restrict__ deg, int* __restrict__ rowg,
                          unsigned short* __restrict__ colbuf) {
  int t = blockIdx.x & 7;
  int b = blockIdx.x >> 3;
  __shared__ unsigned short sbuf[DF_CAP]; // 14.8KB
  __shared__ int hist[NPB], rowoff[NPB + 1];
  __shared__ int wsum[4];
  int tid = threadIdx.x;
  int cnt = bincur[t * NB + b];
  if (cnt > DF_CAP) cnt = DF_CAP;
  const int* gbuf = binbuf + (size_t)(t * NB + b) * BIN_CAP;
  for (int i = tid; i < NPB; i += 256) hist[i] = 0;
  __syncthreads();
  for (int i = tid; i < cnt; i += 256) atomicAdd(&hist[gbuf[i] >> 16], 1);
  __syncthreads();
  int nb0 = b * NPB;
  for (int dl = tid; dl < NPB; dl += 256) {
    int n = nb0 + dl;
    if (n < N_NODES) deg[t * N_NODES + n] = hist[dl];
  }
  // block exclusive scan of hist[0..NPB)
  int i0 = 2 * tid, i1 = 2 * tid + 1;
  int a0 = (i0 < NPB) ? hist[i0] : 0;
  int a1 = (i1 < NPB) ? hist[i1] : 0;
  int tsum = a0 + a1;
  int lane = tid & 63, wid = tid >> 6;
  int sc = tsum;
  #pragma unroll
  for (int off = 1; off < 64; off <<= 1) {
    int o = __shfl_up(sc, off, 64);
    if (lane >= off) sc += o;
  }
  if (lane == 63) wsum[wid] = sc;
  __syncthreads();
  if (tid == 0) {
    int c = 0;
    for (int k = 0; k < 4; ++k) { int v = wsum[k]; wsum[k] = c; c += v; }
  }
  __syncthreads();
  int excl = wsum[wid] + (sc - tsum);
  if (i0 < NPB) rowoff[i0] = excl;
  if (i1 < NPB) rowoff[i1] = excl + a0;
  if (tid == 0) rowoff[NPB] = cnt;
  __syncthreads();
  int* rg = rowg + (size_t)(t * NB + b) * (NPB + 1);
  for (int i = tid; i <= NPB; i += 256) rg[i] = rowoff[i];
  for (int i = tid; i < NPB; i += 256) hist[i] = 0;   // reuse as cursor
  __syncthreads();
  for (int i = tid; i < cnt; i += 256) {
    int w = gbuf[i];                    // L2-hot re-read
    int dl = w >> 16;
    int pos = rowoff[dl] + atomicAdd(&hist[dl], 1);
    sbuf[pos] = (unsigned short)(w & 0xFFFF);   // LDS scatter (banked, cheap)
  }
  __syncthreads();
  unsigned short* cb = colbuf + (size_t)(t * NB + b) * BIN_CAP;
  for (int i = tid; i < cnt; i += 256) cb[i] = sbuf[i];  // coalesced ushort
}

// K3: s = rsqrt(deg+1) * (x @ conv_w) via bf16 MFMA (16x16x32), bf16 out.
__global__ __launch_bounds__(256) void k_xw(const float* __restrict__ x,
                                            const float* __restrict__ w,
                                            const int* __restrict__ deg,
                                            unsigned short* __restrict__ s) {
  int t = blockIdx.x & 7;
  int nb = blockIdx.x >> 3;
  int wave = threadIdx.x >> 6, lane = threadIdx.x & 63;
  int node0 = nb * 64 + wave * 16;
  if (node0 >= N_NODES) return;         // 50000 = 781*64 + 16: clean tail
  int m = lane & 15, kg = lane >> 4;
  const float4* xr = reinterpret_cast<const float4*>(
      x + ((size_t)t * N_NODES + node0 + m) * F_DIM + kg * 8);
  short8 a0 = pack8(xr[0], xr[1]);      // k = kg*8 + 0..7
  short8 a1 = pack8(xr[8], xr[9]);      // k = 32 + kg*8 + 0..7
  const float* wb0 = w + (kg * 8) * H_DIM + m;
  const float* wb1 = wb0 + 32 * H_DIM;
  short8 b00, b01, b10, b11;            // b{khalf}{hhalf}
  #pragma unroll
  for (int j = 0; j < 8; ++j) {
    b00[j] = (short)f2bf(wb0[j * H_DIM]);
    b01[j] = (short)f2bf(wb0[j * H_DIM + 16]);
    b10[j] = (short)f2bf(wb1[j * H_DIM]);
    b11[j] = (short)f2bf(wb1[j * H_DIM + 16]);
  }
  f32x4 acc0 = {0.f, 0.f, 0.f, 0.f}, acc1 = {0.f, 0.f, 0.f, 0.f};
  acc0 = __builtin_amdgcn_mfma_f32_16x16x32_bf16(a0, b00, acc0, 0, 0, 0);
  acc0 = __builtin_amdgcn_mfma_f32_16x16x32_bf16(a1, b10, acc0, 0, 0, 0);
  acc1 = __builtin_amdgcn_mfma_f32_16x16x32_bf16(a0, b01, acc1, 0, 0, 0);
  acc1 = __builtin_amdgcn_mfma_f32_16x16x32_bf16(a1, b11, acc1, 0, 0, 0);
  unsigned short* sbase = s + ((size_t)t * N_NODES + node0) * H_DIM;
  #pragma unroll
  for (int r = 0; r < 4; ++r) {
    int row = kg * 4 + r;
    float dinv = rsqrtf((float)(deg[t * N_NODES + node0 + row] + 1));
    sbase[(size_t)row * H_DIM + m]      = f2bf(acc0[r] * dinv);
    sbase[(size_t)row * H_DIM + 16 + m] = f2bf(acc1[r] * dinv);
  }
}

// K4: work-stealing gather with guaranteed LDS col staging + fused pooled
// reduction (atomicAdd into seq_raw). t = bid&7 (XCD-pinned).
__global__ void k_gather4(const unsigned short* __restrict__ s,
                          const unsigned short* __restrict__ colbuf,
                          const int* __restrict__ rowg, const float* __restrict__ conv_b,
                          float* __restrict__ seq_raw) {
  int bid = blockIdx.x;
  int t = bid & 7;
  int gblk = bid >> 3;                  // 0..NBLK_G3-1
  int base = gblk * NPB3;
  int tid = threadIdx.x;
  int g = tid >> 2, j = tid & 3;        // 64 groups x 4 feature-lanes
  int lane = tid & 63;
  __shared__ unsigned short colstage[CSTAGE];  // 29.6KB
  __shared__ int ro_l[2][NPB + 1];             // 3.1KB
  __shared__ int nextn;
  __shared__ float red[4][32];
  if (tid == 0) nextn = 64;

  int nend = min(base + NPB3, N_NODES);
  int bin0 = base / NPB;
  int bin1 = (nend - 1) / NPB;          // bin0 or bin0+1
  const int* rg0 = rowg + (size_t)(t * NB + bin0) * (NPB + 1);
  for (int i = tid; i <= NPB; i += 256) ro_l[0][i] = rg0[i];
  if (bin1 > bin0) {
    const int* rg1 = rowg + (size_t)(t * NB + bin1) * (NPB + 1);
    for (int i = tid; i <= NPB; i += 256) ro_l[1][i] = rg1[i];
  }
  __syncthreads();
  int dlA0 = base - bin0 * NPB;
  int dlE0 = (bin1 > bin0) ? (NPB - 1) : (nend - 1 - bin0 * NPB);
  int s0 = ro_l[0][dlA0];
  int len0 = ro_l[0][dlE0 + 1] - s0;    // <= DF_CAP
  int len1 = 0;
  if (bin1 > bin0) {
    int dlE1 = nend - 1 - bin1 * NPB;
    len1 = ro_l[1][dlE1 + 1];           // seg1 starts at within-bin offset 0
  }
  {
    const unsigned short* cb0 = colbuf + (size_t)(t * NB + bin0) * BIN_CAP + s0;
    for (int i = tid; i < len0; i += 256) colstage[i] = cb0[i];
    if (len1 > 0) {
      const unsigned short* cb1 = colbuf + (size_t)(t * NB + bin1) * BIN_CAP;
      for (int i = tid; i < len1; i += 256) colstage[len0 + i] = cb1[i];
    }
  }
  __syncthreads();

  const unsigned short* sbase = s + (size_t)t * N_NODES * H_DIM;
  const float4* cb4 = reinterpret_cast<const float4*>(conv_b);
  float4 bb0 = cb4[j * 2], bb1 = cb4[j * 2 + 1];
  float pool[8];
  #pragma unroll
  for (int e = 0; e < 8; ++e) pool[e] = 0.f;
  int idx = g;                          // initial assignment, then steal
  while (idx < NPB3) {
    int n = base + idx;
    if (n < N_NODES) {
      int b = n / NPB;
      int dl = n - b * NPB;
      int bi = b - bin0;                // 0 or 1
      int start = ro_l[bi][dl], end = ro_l[bi][dl + 1];
      int cofs = bi ? len0 : (-s0);     // int offset; p + cofs >= 0 always
      float dinv = rsqrtf((float)(end - start + 1));
      float acc[8];
      #pragma unroll
      for (int e = 0; e < 8; ++e) acc[e] = 0.f;
      uint4 su = *reinterpret_cast<const uint4*>(sbase + (size_t)n * H_DIM + j * 8);
      addbf8(acc, su);                  // self-loop row
      int p = start;
      for (; p + 8 <= end; p += 8) {    // eight independent chains
        int c0 = colstage[p + cofs],     c1 = colstage[p + 1 + cofs];
        int c2 = colstage[p + 2 + cofs], c3 = colstage[p + 3 + cofs];
        int c4 = colstage[p + 4 + cofs], c5 = colstage[p + 5 + cofs];
        int c6 = colstage[p + 6 + cofs], c7 = colstage[p + 7 + cofs];
        uint4 v0 = *reinterpret_cast<const uint4*>(sbase + (size_t)c0 * H_DIM + j * 8);
        uint4 v1 = *reinterpret_cast<const uint4*>(sbase + (size_t)c1 * H_DIM + j * 8);
        uint4 v2 = *reinterpret_cast<const uint4*>(sbase + (size_t)c2 * H_DIM + j * 8);
        uint4 v3 = *reinterpret_cast<const uint4*>(sbase + (size_t)c3 * H_DIM + j * 8);
        uint4 v4 = *reinterpret_cast<const uint4*>(sbase + (size_t)c4 * H_DIM + j * 8);
        uint4 v5 = *reinterpret_cast<const uint4*>(sbase + (size_t)c5 * H_DIM + j * 8);
        uint4 v6 = *reinterpret_cast<const uint4*>(sbase + (size_t)c6 * H_DIM + j * 8);
        uint4 v7 = *reinterpret_cast<const uint4*>(sbase + (size_t)c7 * H_DIM + j * 8);
        addbf8(acc, v0); addbf8(acc, v1); addbf8(acc, v2); addbf8(acc, v3);
        addbf8(acc, v4); addbf8(acc, v5); addbf8(acc, v6); addbf8(acc, v7);
      }
      for (; p + 4 <= end; p += 4) {
        int c0 = colstage[p + cofs],     c1 = colstage[p + 1 + cofs];
        int c2 = colstage[p + 2 + cofs], c3 = colstage[p + 3 + cofs];
        uint4 v0 = *reinterpret_cast<const uint4*>(sbase + (size_t)c0 * H_DIM + j * 8);
        uint4 v1 = *reinterpret_cast<const uint4*>(sbase + (size_t)c1 * H_DIM + j * 8);
        uint4 v2 = *reinterpret_cast<const uint4*>(sbase + (size_t)c2 * H_DIM + j * 8);
        uint4 v3 = *reinterpret_cast<const uint4*>(sbase + (size_t)c3 * H_DIM + j * 8);
        addbf8(acc, v0); addbf8(acc, v1); addbf8(acc, v2); addbf8(acc, v3);
      }
      for (; p < end; ++p) {
        int c0 = colstage[p + cofs];
        uint4 v0 = *reinterpret_cast<const uint4*>(sbase + (size_t)c0 * H_DIM + j * 8);
        addbf8(acc, v0);
      }
      pool[0] += fmaxf(acc[0] * dinv + bb0.x, 0.f);
      pool[1] += fmaxf(acc[1] * dinv + bb0.y, 0.f);
      pool[2] += fmaxf(acc[2] * dinv + bb0.z, 0.f);
      pool[3] += fmaxf(acc[3] * dinv + bb0.w, 0.f);
      pool[4] += fmaxf(acc[4] * dinv + bb1.x, 0.f);
      pool[5] += fmaxf(acc[5] * dinv + bb1.y, 0.f);
      pool[6] += fmaxf(acc[6] * dinv + bb1.z, 0.f);
      pool[7] += fmaxf(acc[7] * dinv + bb1.w, 0.f);
    }
    // steal next node (group-uniform: leader atomicAdd, broadcast in-group)
    int nn = 0;
    if ((lane & 3) == 0) nn = atomicAdd(&nextn, 1);
    nn = __shfl(nn, lane & 60, 64);
    idx = nn;
  }
  // reduce across the 16 groups of each wave (classes = lane&3)
  #pragma unroll
  for (int off = 4; off < 64; off <<= 1) {
    #pragma unroll
    for (int e = 0; e < 8; ++e) pool[e] += __shfl_xor(pool[e], off, 64);
  }
  int wid = tid >> 6;
  if (lane < 4) {
    #pragma unroll
    for (int e = 0; e < 8; ++e) red[wid][lane * 8 + e] = pool[e];
  }
  __syncthreads();
  if (tid < 32) {
    float sum = red[0][tid] + red[1][tid] + red[2][tid] + red[3][tid];
    atomicAdd(&seq_raw[t * H_DIM + tid], sum);
  }
}

// K6: gate-x precompute (all t) + sequential LSTM + fc head, one block.
__global__ void k_lstm(const float* __restrict__ seq_raw, const float* __restrict__ w_ih,
                       const float* __restrict__ b_ih, const float* __restrict__ b_hh,
                       const float* __restrict__ w_hh, const float* __restrict__ fc_w,
                       const float* __restrict__ fc_b, float* __restrict__ out) {
  __shared__ float xb[T_DIM][32];
  __shared__ float gxs[T_DIM][256];
  __shared__ float hbuf[64], cbuf[64], gates[256];
  int j = threadIdx.x;                  // 256
  if (j < T_DIM * 32) xb[j >> 5][j & 31] = seq_raw[j] * (1.0f / (float)N_NODES);
  if (j < 64) { hbuf[j] = 0.f; cbuf[j] = 0.f; }
  __syncthreads();
  float bsum = b_ih[j] + b_hh[j];
  for (int t = 0; t < T_DIM; ++t) {
    float gacc = bsum;
    #pragma unroll
    for (int k = 0; k < 32; ++k) gacc += w_ih[j * 32 + k] * xb[t][k];
    gxs[t][j] = gacc;
  }
  __syncthreads();
  for (int t = 0; t < T_DIM; ++t) {
    float g = gxs[t][j];
    #pragma unroll 8
    for (int k = 0; k < 64; ++k) g += w_hh[j * 64 + k] * hbuf[k];
    gates[j] = g;
    __syncthreads();
    if (j < 64) {
      float ii = 1.f / (1.f + expf(-gates[j]));
      float ff = 1.f / (1.f + expf(-gates[64 + j]));
      float gg = tanhf(gates[128 + j]);
      float oo = 1.f / (1.f + expf(-gates[192 + j]));
      float c = ff * cbuf[j] + ii * gg;
      cbuf[j] = c;
      hbuf[j] = oo * tanhf(c);
    }
    __syncthreads();
  }
  if (j == 0) {
    float acc = 0.f;
    for (int k = 0; k < 64; ++k) acc += hbuf[k] * fc_w[k];
    out[0] = acc + fc_b[0];
  }
}

extern "C" void kernel_launch(void* const* d_in, const int* in_sizes, int n_in,
                              void* d_out, int out_size, void* d_ws, size_t ws_size,
                              hipStream_t stream) {
  const float* x      = (const float*)d_in[0];
  const int*   ei     = (const int*)  d_in[1];
  const float* conv_w = (const float*)d_in[2];
  const float* conv_b = (const float*)d_in[3];
  const float* w_ih   = (const float*)d_in[4];
  const float* w_hh   = (const float*)d_in[5];
  const float* b_ih   = (const float*)d_in[6];
  const float* b_hh   = (const float*)d_in[7];
  const float* fc_w   = (const float*)d_in[8];
  const float* fc_b   = (const float*)d_in[9];
  float* out = (float*)d_out;

  char* wsb = (char*)d_ws;
  size_t off = 0;
  auto alloc = [&](size_t bytes) {
    void* p = wsb + off;
    off = (off + bytes + 255) & ~(size_t)255;
    return p;
  };
  int* bincur   = (int*)alloc(sizeof(int) * T_DIM * NB);                    // 4 KB
  int* binbuf   = (int*)alloc(sizeof(int) * (size_t)T_DIM * NB * BIN_CAP);  // 32 MB
  unsigned short* colbuf = (unsigned short*)alloc(sizeof(unsigned short) * (size_t)T_DIM * NB * BIN_CAP); // 16 MB
  int* deg      = (int*)alloc(sizeof(int) * T_DIM * N_NODES);               // 1.6 MB
  int* rowg     = (int*)alloc(sizeof(int) * (size_t)T_DIM * NB * (NPB + 1)); // 1.6 MB
  unsigned short* s = (unsigned short*)alloc(sizeof(unsigned short) * (size_t)T_DIM * N_NODES * H_DIM); // 25.6 MB
  float* seq_raw  = (float*)alloc(sizeof(float) * T_DIM * H_DIM);

  (void)hipMemsetAsync(bincur, 0, sizeof(int) * T_DIM * NB, stream);
  (void)hipMemsetAsync(seq_raw, 0, sizeof(float) * T_DIM * H_DIM, stream);

  k_part<<<(E_EDGES / CHUNK_A) * T_DIM, 256, 0, stream>>>(ei, bincur, binbuf);
  k_degfill<<<NB * T_DIM, 256, 0, stream>>>(bincur, binbuf, deg, rowg, colbuf);
  k_xw<<<782 * T_DIM, 256, 0, stream>>>(x, conv_w, deg, s);
  k_gather4<<<NBLK_G3 * T_DIM, 256, 0, stream>>>(s, colbuf, rowg, conv_b, seq_raw);
  k_lstm<<<1, 256, 0, stream>>>(seq_raw, w_ih, b_ih, b_hh, w_hh, fc_w, fc_b, out);
}